// Round 9
// baseline (145.222 us; speedup 1.0000x reference)
//
#include <hip/hip_runtime.h>
#include <math.h>

#define NPTS 512
#define NBATCH 64
#define NROWS (NPTS * NBATCH)   // 32768
#define LARGEV 1000000.0f
#define RPW 4                   // rows per wave in the MLP phases

typedef float v2f __attribute__((ext_vector_type(2)));

__device__ __forceinline__ float rdlane(float v, int l) {
  return __uint_as_float((unsigned)__builtin_amdgcn_readlane((int)__float_as_uint(v), l));
}

// acc = s*w + acc on both components (v_pk_fma_f32 when ISel can pack).
__device__ __forceinline__ void pk_fma(v2f& acc, float s, v2f w) {
  acc = __builtin_elementwise_fma(w, (v2f){s, s}, acc);
}

// ---------------------------------------------------------------------------
// Round-9 = round-8 arithmetic, re-tiled for occupancy:
//   2048 blocks x (16 rows x 16 j-chunks); 32 pair-iters/lane (was 64).
//   LDS ~24.7KB -> 6 blocks/CU by LDS (was grid-capped at 4); finer blocks
//   smooth the tail. r8 evidence: conflicts 2.96M->0 changed nothing ->
//   bound is VALU issue + idle (VALUBusy 70%, Occ 31%); this raises
//   resident waves without touching the per-pair op count.
// MLP: RPW=4 (wave owns rows 4w..4w+3). Same per-row cost; W2 L1 traffic
//   doubles per CU (~2MB) - overlapped, acceptable.
// Everything else r8-verified: NaN masking, packed nested-threshold
// counters, fire-and-forget DS-atomic sector scatter on [slot][tid] planes
// (bank=tid%32, conflict-free; NaN never wins a u32 min vs LARGEV bits),
// same-wave xs handoff (writer lane il*16 is in consumer wave il/4).
// __f*_rn keeps dist bit-identical to numpy (threshold compares exact).
// ---------------------------------------------------------------------------
__global__ __launch_bounds__(256, 4) void fused_kernel(const float* __restrict__ pos,
    const void* __restrict__ kpm,
    const float* __restrict__ W1, const float* __restrict__ b1,
    const float* __restrict__ gamma, const float* __restrict__ beta,
    const float* __restrict__ W2, const float* __restrict__ b2,
    float* __restrict__ out) {
  __shared__ float2 sp[NPTS];            //  4096 B
  __shared__ unsigned scru[2 * 9 * 256]; // 18432 B: [0..8]=min bits, [9..17]=count
  __shared__ float xs[16 * 33];          //  2112 B  per-row feature vectors
  __shared__ int sflag;
  const int b  = blockIdx.x >> 5;
  const int i0 = (blockIdx.x & 31) << 4;
  const int tid = threadIdx.x;

  // ---- inline mask-dtype sniff over first 2KB of the raw mask buffer ----
  if (tid == 0) sflag = 0;
  __syncthreads();
  {
    const unsigned int* rw = (const unsigned int*)kpm;
    const unsigned int w0 = rw[tid];
    const unsigned int w1 = rw[tid + 256];
    int f = 0;
    if (w0 == 0x3f800000u || w1 == 0x3f800000u) f |= 2;   // float 1.0 pattern
    if (w0 > 1u || w1 > 1u) f |= 1;                        // packed-byte pattern
    if (f) atomicOr(&sflag, f);
  }
  __syncthreads();
  const int fmt = sflag;   // 2=>f32, 1=>bytes, 0=>i32 (f32 priority)

  // ---- stage positions, NaN-ifying masked points; init sector planes ----
  for (int t = tid; t < NPTS; t += 256) {
    bool m;
    if (fmt & 2)      m = ((const float*)kpm)[b * NPTS + t] != 0.0f;
    else if (fmt & 1) m = ((const unsigned char*)kpm)[b * NPTS + t] != 0;
    else              m = ((const int*)kpm)[b * NPTS + t] != 0;
    float2 p = ((const float2*)pos)[b * NPTS + t];
    if (m) { p.x = __builtin_nanf(""); p.y = p.x; }
    sp[t] = p;
  }
#pragma unroll
  for (int k = 0; k < 9; ++k) {
    scru[k * 256 + tid] = __float_as_uint(LARGEV);   // per-thread min cell
    scru[2304 + k * 256 + tid] = 0u;                 // per-thread count cell
  }
  __syncthreads();

  const int il = tid >> 4;       // row within block: 0..15
  const int jc = tid & 15;       // j-chunk: 0..15
  const int i  = i0 + il;
  const float2 pi = ((const float2*)pos)[b * NPTS + i];   // real anchor (global)

  unsigned cu = 0u, cd = 0u, cl = 0u;   // packed counts: byte0=w3..byte3=w12
  float dmin0 = LARGEV, dmin1 = LARGEV, dmin2 = LARGEV;
  float sumd = 0.0f;
  int vcn = 0;

#pragma unroll 4
  for (int jj = 0; jj < 32; ++jj) {
    const int j = (jj << 4) + jc;
    const float2 pj = sp[j];
    const float dx = __fsub_rn(pj.x, pi.x);
    const float dy = __fsub_rn(pj.y, pi.y);
    const float d2 = __fadd_rn(__fadd_rn(__fmul_rn(dx, dx), __fmul_rn(dy, dy)), 1e-8f);
    float dist = __fsqrt_rn(d2);
    dist = (j == i) ? __builtin_nanf("") : dist;          // self -> NaN

    const float hdy = __fmul_rn(fabsf(dy), 0.5f);
    const bool up = dx > hdy;
    const bool dn = dx < -hdy;

    const bool w3  = dist <  3.0f;
    const bool w5  = dist <  5.0f;
    const bool w8  = dist <  8.0f;
    const bool w12 = dist < 12.0f;
    const unsigned a = w3 ? 0x01010101u
                     : (w5 ? 0x01010100u
                     : (w8 ? 0x01010000u
                     : (w12 ? 0x01000000u : 0u)));
    cu += up ? a : 0u;
    cd += dn ? a : 0u;
    cl += (!up && !dn) ? a : 0u;

    dmin0 = fminf(dmin0, up ? dist : LARGEV);
    dmin1 = fminf(dmin1, dn ? dist : LARGEV);
    dmin2 = fminf(dmin2, (!up && !dn) ? dist : LARGEV);   // NaN dropped (minNum)

    const bool c = dist < 1.0e30f;                         // NaN -> false
    sumd += c ? dist : 0.0f;
    vcn  += c ? 1 : 0;

    // octant sector; dy==0,dx>0 -> s4 (angle 0); dy==0,dx<=0 / NaN -> 8
    const int slot = (dy > 0.0f)
        ? ((dx > 0.0f) ? ((dy < dx) ? 4 : 5) : ((-dx < dy) ? 6 : 7))
        : ((dy < 0.0f) ? ((dx < 0.0f) ? ((dx < dy) ? 0 : 1) : ((dx < -dy) ? 2 : 3))
                       : ((dx > 0.0f) ? 4 : 8));
    const int idx = slot * 256 + tid;
    atomicMin(&scru[idx], __float_as_uint(dist));   // ds_min_u32, no return
    atomicAdd(&scru[2304 + idx], 1u);               // ds_add_u32, no return
  }

  // ---- readback own sector cells (same-thread DS order) + unpack ----
  float cnt[12];
  cnt[0] = (float)(cu & 0xffu);  cnt[3] = (float)((cu >> 8) & 0xffu);
  cnt[6] = (float)((cu >> 16) & 0xffu);  cnt[9]  = (float)(cu >> 24);
  cnt[1] = (float)(cd & 0xffu);  cnt[4] = (float)((cd >> 8) & 0xffu);
  cnt[7] = (float)((cd >> 16) & 0xffu);  cnt[10] = (float)(cd >> 24);
  cnt[2] = (float)(cl & 0xffu);  cnt[5] = (float)((cl >> 8) & 0xffu);
  cnt[8] = (float)((cl >> 16) & 0xffu);  cnt[11] = (float)(cl >> 24);
  float scnt[8], smin[8];
#pragma unroll
  for (int k = 0; k < 8; ++k) {
    smin[k] = __uint_as_float(scru[k * 256 + tid]);
    scnt[k] = (float)scru[2304 + k * 256 + tid];
  }
  float vcnt = (float)vcn;
  float dmin[3] = {dmin0, dmin1, dmin2};

  // ---- reduce 16 chunk partials (lanes differing in bits 0..3) ----
#pragma unroll
  for (int k = 0; k < 12; ++k) {
    cnt[k] += __shfl_xor(cnt[k], 1); cnt[k] += __shfl_xor(cnt[k], 2);
    cnt[k] += __shfl_xor(cnt[k], 4); cnt[k] += __shfl_xor(cnt[k], 8);
  }
#pragma unroll
  for (int k = 0; k < 8; ++k) {
    scnt[k] += __shfl_xor(scnt[k], 1); scnt[k] += __shfl_xor(scnt[k], 2);
    scnt[k] += __shfl_xor(scnt[k], 4); scnt[k] += __shfl_xor(scnt[k], 8);
  }
  sumd += __shfl_xor(sumd, 1); sumd += __shfl_xor(sumd, 2);
  sumd += __shfl_xor(sumd, 4); sumd += __shfl_xor(sumd, 8);
  vcnt += __shfl_xor(vcnt, 1); vcnt += __shfl_xor(vcnt, 2);
  vcnt += __shfl_xor(vcnt, 4); vcnt += __shfl_xor(vcnt, 8);
#pragma unroll
  for (int k = 0; k < 3; ++k) {
    dmin[k] = fminf(dmin[k], __shfl_xor(dmin[k], 1));
    dmin[k] = fminf(dmin[k], __shfl_xor(dmin[k], 2));
    dmin[k] = fminf(dmin[k], __shfl_xor(dmin[k], 4));
    dmin[k] = fminf(dmin[k], __shfl_xor(dmin[k], 8));
  }
#pragma unroll
  for (int k = 0; k < 8; ++k) {
    smin[k] = fminf(smin[k], __shfl_xor(smin[k], 1));
    smin[k] = fminf(smin[k], __shfl_xor(smin[k], 2));
    smin[k] = fminf(smin[k], __shfl_xor(smin[k], 4));
    smin[k] = fminf(smin[k], __shfl_xor(smin[k], 8));
  }

  // ---- park row il's 33 feats in LDS (writer lane il*16 is in the same
  //      wave that consumes rows 4w..4w+3 below -> no barrier needed) ----
  if (jc == 0) {
    float* f = &xs[il * 33];
#pragma unroll
    for (int k = 0; k < 12; ++k) f[k] = cnt[k];
    f[12] = fminf(dmin[0] * 0.1f, 1.0f);
    f[13] = fminf(dmin[1] * 0.1f, 1.0f);
    f[14] = fminf(dmin[2] * 0.1f, 1.0f);
#pragma unroll
    for (int k = 0; k < 8; ++k) {
      f[15 + 2 * k] = scnt[k];
      f[16 + 2 * k] = fminf(smin[k] * 0.1f, 1.0f);
    }
    f[31] = cnt[9] + cnt[10] + cnt[11];
    f[32] = fminf(sumd / fmaxf(vcnt, 1.0f) * 0.1f, 1.0f);
  }

  // ======================= MLP section (RPW=4) ============================
  const int w = tid >> 6;
  const int l = tid & 63;
  const float* __restrict__ xsf = xs + w * (RPW * 33);   // wave's 132 floats

  float xreg[3];
  xreg[0] = xsf[l];
  xreg[1] = xsf[64 + l];
  xreg[2] = (l < 4) ? xsf[128 + l] : 0.0f;

  const v2f b1v = ((const v2f*)b1)[l];
  const v2f gav = ((const v2f*)gamma)[l];
  const v2f bev = ((const v2f*)beta)[l];
  const v2f b2v = ((const v2f*)b2)[l];
  const v2f* __restrict__ W1v = (const v2f*)W1;
  const v2f* __restrict__ W2v = (const v2f*)W2;

  // ---- phase 1: h = x @ W1 + b1 (readlane broadcast + packed fma) ----
  v2f h[RPW];
#pragma unroll
  for (int r = 0; r < RPW; ++r) h[r] = b1v;
#pragma unroll
  for (int k = 0; k < 33; ++k) {
    const v2f wv = W1v[k * 64 + l];
#pragma unroll
    for (int r = 0; r < RPW; ++r) {
      const int v = r * 33 + k;                 // compile-time, max 131
      pk_fma(h[r], rdlane(xreg[v >> 6], v & 63), wv);
    }
  }

  // ---- phase 2: LayerNorm + exact GELU (in registers) ----
  float g0[RPW], g1[RPW];
#pragma unroll
  for (int r = 0; r < RPW; ++r) {
    float s = h[r].x + h[r].y;
#pragma unroll
    for (int o = 32; o > 0; o >>= 1) s += __shfl_xor(s, o);
    const float mu = s * 0.0078125f;
    const float d0 = h[r].x - mu, d1 = h[r].y - mu;
    float v = d0 * d0 + d1 * d1;
#pragma unroll
    for (int o = 32; o > 0; o >>= 1) v += __shfl_xor(v, o);
    const float inv = 1.0f / __fsqrt_rn(v * 0.0078125f + 1e-5f);
    float a = d0 * inv * gav.x + bev.x;
    float bb = d1 * inv * gav.y + bev.y;
    g0[r] = 0.5f * a * (1.0f + erff(a * 0.70710678118654752f));
    g1[r] = 0.5f * bb * (1.0f + erff(bb * 0.70710678118654752f));
  }

  // ---- phase 3: out = g @ W2 + b2 (readlane broadcast + packed fma) ----
  v2f acc[RPW];
#pragma unroll
  for (int r = 0; r < RPW; ++r) acc[r] = b2v;
#pragma unroll 8
  for (int kp = 0; kp < 64; ++kp) {            // k = 2*kp, 2*kp+1
    const v2f wva = W2v[(2 * kp) * 64 + l];
    const v2f wvb = W2v[(2 * kp + 1) * 64 + l];
#pragma unroll
    for (int r = 0; r < RPW; ++r) {
      pk_fma(acc[r], rdlane(g0[r], kp), wva);
      pk_fma(acc[r], rdlane(g1[r], kp), wvb);
    }
  }
  const int row0 = blockIdx.x * 16 + RPW * w;  // == b*512 + i0 + w*4
#pragma unroll
  for (int r = 0; r < RPW; ++r) {
    ((v2f*)out)[(size_t)(row0 + r) * 64 + l] = acc[r];
  }
}

extern "C" void kernel_launch(void* const* d_in, const int* in_sizes, int n_in,
                              void* d_out, int out_size, void* d_ws, size_t ws_size,
                              hipStream_t stream) {
  const float* positions = (const float*)d_in[0];
  const void*  kpm_raw   = d_in[1];
  const float* W1    = (const float*)d_in[2];
  const float* b1    = (const float*)d_in[3];
  const float* gamma = (const float*)d_in[4];
  const float* beta  = (const float*)d_in[5];
  const float* W2    = (const float*)d_in[6];
  const float* b2    = (const float*)d_in[7];
  float* out = (float*)d_out;

  fused_kernel<<<NBATCH * 32, 256, 0, stream>>>(positions, kpm_raw,
      W1, b1, gamma, beta, W2, b2, out);
}

// Round 10
// 142.187 us; speedup vs baseline: 1.0213x; 1.0213x over previous
//
#include <hip/hip_runtime.h>
#include <math.h>

#define NPTS 512
#define NBATCH 64
#define NROWS (NPTS * NBATCH)   // 32768
#define LARGEV 1000000.0f
#define RPW 8                   // rows per wave in the MLP phases

typedef float v2f __attribute__((ext_vector_type(2)));

__device__ __forceinline__ float rdlane(float v, int l) {
  return __uint_as_float((unsigned)__builtin_amdgcn_readlane((int)__float_as_uint(v), l));
}

// acc = s*w + acc on both components (v_pk_fma_f32 when ISel can pack).
__device__ __forceinline__ void pk_fma(v2f& acc, float s, v2f w) {
  acc = __builtin_elementwise_fma(w, (v2f){s, s}, acc);
}

// ---------------------------------------------------------------------------
// Round-10 = r8 base (best: 84us) + feature-loop diet. Evidence: r8
// (conflicts->0) and r9 (2x blocks) both neutral -> kernel is dependency-
// latency bound, not conflict/occupancy bound. Changes:
//  1. threshold compares in d^2 domain -- sqrt leaves the count critical
//     path. Equivalence for correctly-rounded f32 sqrt (proven per cutoff):
//     dist<3  <=> d2 < 9.0
//     dist<5  <=> d2 < 25 - 2^-19  (0x41C7FFFF; d2=25-2^-19 has sqrt
//                                   rounding UP to 5.0 -> plain <25 wrong)
//     dist<8  <=> d2 < 64.0
//     dist<12 <=> d2 < 144.0
//  2. cl (lateral) counts derived post-loop: cl = asum - cu - cd (byte-exact,
//     each byte <= 64).
//  3. direction-min scatter -> DS atomicMin on [dir][tid] planes (NaN-bits
//     0x7FC00000 never win a u32 min vs LARGEV bits 0x497...).
//  4. vcnt from block masked-count M (ballot; r6-proven), not per-iter.
// MLP section: byte-for-byte r8 (readlane broadcasts; VGPR 64, no spill).
// __f*_rn keeps d2 bit-identical to numpy.
// ---------------------------------------------------------------------------
__global__ __launch_bounds__(256, 4) void fused_kernel(const float* __restrict__ pos,
    const void* __restrict__ kpm,
    const float* __restrict__ W1, const float* __restrict__ b1,
    const float* __restrict__ gamma, const float* __restrict__ beta,
    const float* __restrict__ W2, const float* __restrict__ b2,
    float* __restrict__ out) {
  __shared__ float2 sp[NPTS];             //  4096 B
  __shared__ unsigned scru[21 * 256];     // 21504 B: planes 0-8 sector min,
                                          //          9-17 sector cnt, 18-20 dir min
  __shared__ float xs[32 * 33];           //  4224 B  per-row feature vectors
  __shared__ int sflag, sMasked;
  const int b  = blockIdx.x >> 4;
  const int i0 = (blockIdx.x & 15) << 5;
  const int tid = threadIdx.x;

  // ---- inline mask-dtype sniff over first 2KB of the raw mask buffer ----
  if (tid == 0) { sflag = 0; sMasked = 0; }
  __syncthreads();
  {
    const unsigned int* rw = (const unsigned int*)kpm;
    const unsigned int w0 = rw[tid];
    const unsigned int w1 = rw[tid + 256];
    int f = 0;
    if (w0 == 0x3f800000u || w1 == 0x3f800000u) f |= 2;   // float 1.0 pattern
    if (w0 > 1u || w1 > 1u) f |= 1;                        // packed-byte pattern
    if (f) atomicOr(&sflag, f);
  }
  __syncthreads();
  const int fmt = sflag;   // 2=>f32, 1=>bytes, 0=>i32 (f32 priority)

  // ---- stage positions (NaN for masked), count masked via ballot ----
  for (int t = tid; t < NPTS; t += 256) {
    bool m;
    if (fmt & 2)      m = ((const float*)kpm)[b * NPTS + t] != 0.0f;
    else if (fmt & 1) m = ((const unsigned char*)kpm)[b * NPTS + t] != 0;
    else              m = ((const int*)kpm)[b * NPTS + t] != 0;
    float2 p = ((const float2*)pos)[b * NPTS + t];
    if (m) { p.x = __builtin_nanf(""); p.y = p.x; }
    sp[t] = p;
    unsigned long long bal = __ballot(m);
    if ((tid & 63) == 0) atomicAdd(&sMasked, __popcll(bal));
  }
#pragma unroll
  for (int k = 0; k < 9; ++k) {
    scru[k * 256 + tid] = __float_as_uint(LARGEV);   // sector min cells
    scru[2304 + k * 256 + tid] = 0u;                 // sector count cells
  }
#pragma unroll
  for (int k = 0; k < 3; ++k)
    scru[4608 + k * 256 + tid] = __float_as_uint(LARGEV);  // dir min cells
  __syncthreads();
  const int M = sMasked;

  const int il = tid >> 3;       // row within block: 0..31
  const int jc = tid & 7;        // j-chunk: 0..7
  const int i  = i0 + il;
  const float2 pi = ((const float2*)pos)[b * NPTS + i];   // real anchor (global)

  const float T5 = __uint_as_float(0x41C7FFFFu);   // 25 - 2^-19
  unsigned cu = 0u, cd = 0u, asum = 0u;   // packed: byte0=w3..byte3=w12
  float sumd = 0.0f;

#pragma unroll 4
  for (int jj = 0; jj < 64; ++jj) {
    const int j = (jj << 3) + jc;
    const float2 pj = sp[j];
    const float dx = __fsub_rn(pj.x, pi.x);
    const float dy = __fsub_rn(pj.y, pi.y);
    float d2 = __fadd_rn(__fadd_rn(__fmul_rn(dx, dx), __fmul_rn(dy, dy)), 1e-8f);
    d2 = (j == i) ? __builtin_nanf("") : d2;              // self -> NaN

    const float hdy = __fmul_rn(fabsf(dy), 0.5f);
    const bool up = dx > hdy;
    const bool dn = dx < -hdy;

    // thresholds in d2 domain (sqrt off this path); NaN fails all
    const unsigned a = (d2 < 9.0f)  ? 0x01010101u
                     : ((d2 < T5)    ? 0x01010100u
                     : ((d2 < 64.0f) ? 0x01010000u
                     : ((d2 < 144.0f) ? 0x01000000u : 0u)));
    asum += a;
    cu += up ? a : 0u;
    cd += dn ? a : 0u;

    const float dist = __fsqrt_rn(d2);                    // NaN-propagating
    sumd += (dist < 1.0e30f) ? dist : 0.0f;               // NaN -> false

    // direction-min scatter (planes 18..20); NaN bits never win u32 min
    const int dir = up ? 0 : (dn ? 1 : 2);
    atomicMin(&scru[4608 + dir * 256 + tid], __float_as_uint(dist));

    // octant sector; dy==0,dx>0 -> s4 (angle 0); dy==0,dx<=0 / NaN -> 8
    const int slot = (dy > 0.0f)
        ? ((dx > 0.0f) ? ((dy < dx) ? 4 : 5) : ((-dx < dy) ? 6 : 7))
        : ((dy < 0.0f) ? ((dx < 0.0f) ? ((dx < dy) ? 0 : 1) : ((dx < -dy) ? 2 : 3))
                       : ((dx > 0.0f) ? 4 : 8));
    const int idx = slot * 256 + tid;
    atomicMin(&scru[idx], __float_as_uint(dist));   // ds_min_u32, no return
    atomicAdd(&scru[2304 + idx], 1u);               // ds_add_u32, no return
  }

  const unsigned clp = asum - cu - cd;   // byte-exact lateral counts

  // ---- readback own cells (same-thread DS order) + unpack ----
  float cnt[12];
  cnt[0] = (float)(cu & 0xffu);  cnt[3] = (float)((cu >> 8) & 0xffu);
  cnt[6] = (float)((cu >> 16) & 0xffu);  cnt[9]  = (float)(cu >> 24);
  cnt[1] = (float)(cd & 0xffu);  cnt[4] = (float)((cd >> 8) & 0xffu);
  cnt[7] = (float)((cd >> 16) & 0xffu);  cnt[10] = (float)(cd >> 24);
  cnt[2] = (float)(clp & 0xffu); cnt[5] = (float)((clp >> 8) & 0xffu);
  cnt[8] = (float)((clp >> 16) & 0xffu); cnt[11] = (float)(clp >> 24);
  float scnt[8], smin[8], dmin[3];
#pragma unroll
  for (int k = 0; k < 8; ++k) {
    smin[k] = __uint_as_float(scru[k * 256 + tid]);
    scnt[k] = (float)scru[2304 + k * 256 + tid];
  }
#pragma unroll
  for (int k = 0; k < 3; ++k)
    dmin[k] = __uint_as_float(scru[4608 + k * 256 + tid]);

  // ---- reduce 8 chunk partials (lanes differing in bits 0..2) ----
#pragma unroll
  for (int k = 0; k < 12; ++k) {
    cnt[k] += __shfl_xor(cnt[k], 1); cnt[k] += __shfl_xor(cnt[k], 2); cnt[k] += __shfl_xor(cnt[k], 4);
  }
#pragma unroll
  for (int k = 0; k < 8; ++k) {
    scnt[k] += __shfl_xor(scnt[k], 1); scnt[k] += __shfl_xor(scnt[k], 2); scnt[k] += __shfl_xor(scnt[k], 4);
  }
  sumd += __shfl_xor(sumd, 1); sumd += __shfl_xor(sumd, 2); sumd += __shfl_xor(sumd, 4);
#pragma unroll
  for (int k = 0; k < 3; ++k) {
    dmin[k] = fminf(dmin[k], __shfl_xor(dmin[k], 1));
    dmin[k] = fminf(dmin[k], __shfl_xor(dmin[k], 2));
    dmin[k] = fminf(dmin[k], __shfl_xor(dmin[k], 4));
  }
#pragma unroll
  for (int k = 0; k < 8; ++k) {
    smin[k] = fminf(smin[k], __shfl_xor(smin[k], 1));
    smin[k] = fminf(smin[k], __shfl_xor(smin[k], 2));
    smin[k] = fminf(smin[k], __shfl_xor(smin[k], 4));
  }

  // ---- park row il's 33 feats in LDS (writer lane il*8 is in the same wave
  //      that consumes rows 8w..8w+7 below -> no barrier needed) ----
  if (jc == 0) {
    const bool own_unmasked = !isnan(sp[i].x);
    const float vcnt = fmaxf((float)(NPTS - M - (own_unmasked ? 1 : 0)), 1.0f);
    float* f = &xs[il * 33];
#pragma unroll
    for (int k = 0; k < 12; ++k) f[k] = cnt[k];
    f[12] = fminf(dmin[0] * 0.1f, 1.0f);
    f[13] = fminf(dmin[1] * 0.1f, 1.0f);
    f[14] = fminf(dmin[2] * 0.1f, 1.0f);
#pragma unroll
    for (int k = 0; k < 8; ++k) {
      f[15 + 2 * k] = scnt[k];
      f[16 + 2 * k] = fminf(smin[k] * 0.1f, 1.0f);
    }
    f[31] = cnt[9] + cnt[10] + cnt[11];
    f[32] = fminf(sumd / vcnt * 0.1f, 1.0f);
  }

  // ======================= MLP section (r8, unchanged) ====================
  const int w = tid >> 6;
  const int l = tid & 63;
  const float* __restrict__ xsf = xs + w * (RPW * 33);   // wave's 264 floats

  float xreg[5];
#pragma unroll
  for (int c = 0; c < 4; ++c) xreg[c] = xsf[c * 64 + l];
  xreg[4] = (l < 8) ? xsf[256 + l] : 0.0f;

  const v2f b1v = ((const v2f*)b1)[l];
  const v2f gav = ((const v2f*)gamma)[l];
  const v2f bev = ((const v2f*)beta)[l];
  const v2f b2v = ((const v2f*)b2)[l];
  const v2f* __restrict__ W1v = (const v2f*)W1;
  const v2f* __restrict__ W2v = (const v2f*)W2;

  // ---- phase 1: h = x @ W1 + b1 (readlane broadcast + packed fma) ----
  v2f h[RPW];
#pragma unroll
  for (int r = 0; r < RPW; ++r) h[r] = b1v;
#pragma unroll
  for (int k = 0; k < 33; ++k) {
    const v2f wv = W1v[k * 64 + l];
#pragma unroll
    for (int r = 0; r < RPW; ++r) {
      const int v = r * 33 + k;                 // compile-time
      pk_fma(h[r], rdlane(xreg[v >> 6], v & 63), wv);
    }
  }

  // ---- phase 2: LayerNorm + exact GELU (in registers) ----
  float g0[RPW], g1[RPW];
#pragma unroll
  for (int r = 0; r < RPW; ++r) {
    float s = h[r].x + h[r].y;
#pragma unroll
    for (int o = 32; o > 0; o >>= 1) s += __shfl_xor(s, o);
    const float mu = s * 0.0078125f;
    const float d0 = h[r].x - mu, d1 = h[r].y - mu;
    float v = d0 * d0 + d1 * d1;
#pragma unroll
    for (int o = 32; o > 0; o >>= 1) v += __shfl_xor(v, o);
    const float inv = 1.0f / __fsqrt_rn(v * 0.0078125f + 1e-5f);
    float a = d0 * inv * gav.x + bev.x;
    float bb = d1 * inv * gav.y + bev.y;
    g0[r] = 0.5f * a * (1.0f + erff(a * 0.70710678118654752f));
    g1[r] = 0.5f * bb * (1.0f + erff(bb * 0.70710678118654752f));
  }

  // ---- phase 3: out = g @ W2 + b2 (readlane broadcast + packed fma) ----
  v2f acc[RPW];
#pragma unroll
  for (int r = 0; r < RPW; ++r) acc[r] = b2v;
#pragma unroll 8
  for (int kp = 0; kp < 64; ++kp) {            // k = 2*kp, 2*kp+1
    const v2f wva = W2v[(2 * kp) * 64 + l];
    const v2f wvb = W2v[(2 * kp + 1) * 64 + l];
#pragma unroll
    for (int r = 0; r < RPW; ++r) {
      pk_fma(acc[r], rdlane(g0[r], kp), wva);
      pk_fma(acc[r], rdlane(g1[r], kp), wvb);
    }
  }
  const int row0 = blockIdx.x * 32 + RPW * w;  // == b*512 + i0 + w*8
#pragma unroll
  for (int r = 0; r < RPW; ++r) {
    ((v2f*)out)[(size_t)(row0 + r) * 64 + l] = acc[r];
  }
}

extern "C" void kernel_launch(void* const* d_in, const int* in_sizes, int n_in,
                              void* d_out, int out_size, void* d_ws, size_t ws_size,
                              hipStream_t stream) {
  const float* positions = (const float*)d_in[0];
  const void*  kpm_raw   = d_in[1];
  const float* W1    = (const float*)d_in[2];
  const float* b1    = (const float*)d_in[3];
  const float* gamma = (const float*)d_in[4];
  const float* beta  = (const float*)d_in[5];
  const float* W2    = (const float*)d_in[6];
  const float* b2    = (const float*)d_in[7];
  float* out = (float*)d_out;

  fused_kernel<<<NBATCH * 16, 256, 0, stream>>>(positions, kpm_raw,
      W1, b1, gamma, beta, W2, b2, out);
}

// Round 11
// 124.555 us; speedup vs baseline: 1.1659x; 1.1416x over previous
//
#include <hip/hip_runtime.h>
#include <math.h>

#define NPTS 512
#define NBATCH 64
#define NROWS (NPTS * NBATCH)   // 32768
#define LARGEV 1000000.0f
#define RPW 8                   // rows per wave in the MLP phases

typedef float v2f __attribute__((ext_vector_type(2)));
typedef short bf16x8 __attribute__((ext_vector_type(8)));   // 8 bf16 = 4 VGPRs
typedef float f32x4 __attribute__((ext_vector_type(4)));

__device__ __forceinline__ float rdlane(float v, int l) {
  return __uint_as_float((unsigned)__builtin_amdgcn_readlane((int)__float_as_uint(v), l));
}
__device__ __forceinline__ void pk_fma(v2f& acc, float s, v2f w) {
  acc = __builtin_elementwise_fma(w, (v2f){s, s}, acc);
}
// manual bf16 RTNE (no header-type dependence); inputs finite here
__device__ __forceinline__ unsigned short f2bf(float f) {
  unsigned u = __float_as_uint(f);
  u += 0x7FFFu + ((u >> 16) & 1u);
  return (unsigned short)(u >> 16);
}
__device__ __forceinline__ float bf2f(unsigned short h) {
  return __uint_as_float(((unsigned)h) << 16);
}

// ---------------------------------------------------------------------------
// W2 pre-split into MFMA B-fragment order (hi/lo bf16 planes in d_ws).
// Frag fi = (n_tile*4 + kk)*64 + lane holds, for lane: n = n_tile*16+(lane&15),
// k = kk*32 + (lane>>4)*8 + j, j=0..7 (element j of the bf16x8).
// ---------------------------------------------------------------------------
__global__ __launch_bounds__(256) void w2prep(const float* __restrict__ W2,
                                              unsigned short* __restrict__ w2p) {
  const int t = blockIdx.x * 256 + threadIdx.x;   // 0..2047
  const int lane = t & 63;
  const int kk = (t >> 6) & 3;
  const int nt = t >> 8;                           // 0..7
  const int n  = nt * 16 + (lane & 15);
  const int k0 = kk * 32 + ((lane >> 4) << 3);
  unsigned hv[4], lv[4];
#pragma unroll
  for (int jp = 0; jp < 4; ++jp) {
    const float va = W2[(k0 + 2 * jp) * 128 + n];
    const float vb = W2[(k0 + 2 * jp + 1) * 128 + n];
    const unsigned short ha = f2bf(va), hb = f2bf(vb);
    const unsigned short la = f2bf(va - bf2f(ha)), lb = f2bf(vb - bf2f(hb));
    hv[jp] = (unsigned)ha | ((unsigned)hb << 16);
    lv[jp] = (unsigned)la | ((unsigned)lb << 16);
  }
  const int fi = (nt * 4 + kk) * 64 + lane;
  ((uint4*)w2p)[fi] = make_uint4(hv[0], hv[1], hv[2], hv[3]);
  ((uint4*)(w2p + 16384))[fi] = make_uint4(lv[0], lv[1], lv[2], lv[3]);
}

// ---------------------------------------------------------------------------
// Fused kernel = r10 feature section + phase1/LN (unchanged) + MFMA phase 3.
// Evidence: VALU issue floor ~24us vs 82us measured; no pipe saturated ->
// stall-bound. Phase 3's 2048 readlane-chained VALU inst (the largest serial
// block) -> 48 mfma_f32_16x16x32_bf16 on the idle matrix pipe.
// Split-bf16 (3 products, drop lo*lo) keeps error <1e-3.
// g staged in LDS [row][k] bf16, row-stride 136 (A-frag ds_read_b128,
// 2-way-free banks), ALIASING the dead sector scratch (barrier-protected).
// Layouts (measured, m89/m91/m120): A[m=lane&15][k=(lane>>4)*8+j],
// B[k=(lane>>4)*8+j][n=lane&15], D: col=lane&15, row=(lane>>4)*4+reg.
// ---------------------------------------------------------------------------
__global__ __launch_bounds__(256, 4) void fused_kernel(const float* __restrict__ pos,
    const void* __restrict__ kpm,
    const float* __restrict__ W1, const float* __restrict__ b1,
    const float* __restrict__ gamma, const float* __restrict__ beta,
    const unsigned short* __restrict__ w2p, const float* __restrict__ b2,
    float* __restrict__ out) {
  __shared__ float2 sp[NPTS];                          //  4096 B
  __shared__ __align__(16) unsigned scru[21 * 256];    // 21504 B; later aliased by gT (17408 B)
  __shared__ float xs[32 * 33];                        //  4224 B
  __shared__ int sflag, sMasked;
  const int b  = blockIdx.x >> 4;
  const int i0 = (blockIdx.x & 15) << 5;
  const int tid = threadIdx.x;

  // ---- inline mask-dtype sniff over first 2KB of the raw mask buffer ----
  if (tid == 0) { sflag = 0; sMasked = 0; }
  __syncthreads();
  {
    const unsigned int* rw = (const unsigned int*)kpm;
    const unsigned int w0 = rw[tid];
    const unsigned int w1 = rw[tid + 256];
    int f = 0;
    if (w0 == 0x3f800000u || w1 == 0x3f800000u) f |= 2;
    if (w0 > 1u || w1 > 1u) f |= 1;
    if (f) atomicOr(&sflag, f);
  }
  __syncthreads();
  const int fmt = sflag;   // 2=>f32, 1=>bytes, 0=>i32

  // ---- stage positions (NaN for masked), count masked via ballot ----
  for (int t = tid; t < NPTS; t += 256) {
    bool m;
    if (fmt & 2)      m = ((const float*)kpm)[b * NPTS + t] != 0.0f;
    else if (fmt & 1) m = ((const unsigned char*)kpm)[b * NPTS + t] != 0;
    else              m = ((const int*)kpm)[b * NPTS + t] != 0;
    float2 p = ((const float2*)pos)[b * NPTS + t];
    if (m) { p.x = __builtin_nanf(""); p.y = p.x; }
    sp[t] = p;
    unsigned long long bal = __ballot(m);
    if ((tid & 63) == 0) atomicAdd(&sMasked, __popcll(bal));
  }
#pragma unroll
  for (int k = 0; k < 9; ++k) {
    scru[k * 256 + tid] = __float_as_uint(LARGEV);
    scru[2304 + k * 256 + tid] = 0u;
  }
#pragma unroll
  for (int k = 0; k < 3; ++k)
    scru[4608 + k * 256 + tid] = __float_as_uint(LARGEV);
  __syncthreads();
  const int M = sMasked;

  const int il = tid >> 3;       // row within block: 0..31
  const int jc = tid & 7;        // j-chunk: 0..7
  const int i  = i0 + il;
  const float2 pi = ((const float2*)pos)[b * NPTS + i];

  const float T5 = __uint_as_float(0x41C7FFFFu);   // 25 - 2^-19
  unsigned cu = 0u, cd = 0u, asum = 0u;
  float sumd = 0.0f;

#pragma unroll 4
  for (int jj = 0; jj < 64; ++jj) {
    const int j = (jj << 3) + jc;
    const float2 pj = sp[j];
    const float dx = __fsub_rn(pj.x, pi.x);
    const float dy = __fsub_rn(pj.y, pi.y);
    float d2 = __fadd_rn(__fadd_rn(__fmul_rn(dx, dx), __fmul_rn(dy, dy)), 1e-8f);
    d2 = (j == i) ? __builtin_nanf("") : d2;

    const float hdy = __fmul_rn(fabsf(dy), 0.5f);
    const bool up = dx > hdy;
    const bool dn = dx < -hdy;

    const unsigned a = (d2 < 9.0f)  ? 0x01010101u
                     : ((d2 < T5)    ? 0x01010100u
                     : ((d2 < 64.0f) ? 0x01010000u
                     : ((d2 < 144.0f) ? 0x01000000u : 0u)));
    asum += a;
    cu += up ? a : 0u;
    cd += dn ? a : 0u;

    const float dist = __fsqrt_rn(d2);
    sumd += (dist < 1.0e30f) ? dist : 0.0f;

    const int dir = up ? 0 : (dn ? 1 : 2);
    atomicMin(&scru[4608 + dir * 256 + tid], __float_as_uint(dist));

    const int slot = (dy > 0.0f)
        ? ((dx > 0.0f) ? ((dy < dx) ? 4 : 5) : ((-dx < dy) ? 6 : 7))
        : ((dy < 0.0f) ? ((dx < 0.0f) ? ((dx < dy) ? 0 : 1) : ((dx < -dy) ? 2 : 3))
                       : ((dx > 0.0f) ? 4 : 8));
    const int idx = slot * 256 + tid;
    atomicMin(&scru[idx], __float_as_uint(dist));
    atomicAdd(&scru[2304 + idx], 1u);
  }

  const unsigned clp = asum - cu - cd;

  float cnt[12];
  cnt[0] = (float)(cu & 0xffu);  cnt[3] = (float)((cu >> 8) & 0xffu);
  cnt[6] = (float)((cu >> 16) & 0xffu);  cnt[9]  = (float)(cu >> 24);
  cnt[1] = (float)(cd & 0xffu);  cnt[4] = (float)((cd >> 8) & 0xffu);
  cnt[7] = (float)((cd >> 16) & 0xffu);  cnt[10] = (float)(cd >> 24);
  cnt[2] = (float)(clp & 0xffu); cnt[5] = (float)((clp >> 8) & 0xffu);
  cnt[8] = (float)((clp >> 16) & 0xffu); cnt[11] = (float)(clp >> 24);
  float scnt[8], smin[8], dmin[3];
#pragma unroll
  for (int k = 0; k < 8; ++k) {
    smin[k] = __uint_as_float(scru[k * 256 + tid]);
    scnt[k] = (float)scru[2304 + k * 256 + tid];
  }
#pragma unroll
  for (int k = 0; k < 3; ++k)
    dmin[k] = __uint_as_float(scru[4608 + k * 256 + tid]);

#pragma unroll
  for (int k = 0; k < 12; ++k) {
    cnt[k] += __shfl_xor(cnt[k], 1); cnt[k] += __shfl_xor(cnt[k], 2); cnt[k] += __shfl_xor(cnt[k], 4);
  }
#pragma unroll
  for (int k = 0; k < 8; ++k) {
    scnt[k] += __shfl_xor(scnt[k], 1); scnt[k] += __shfl_xor(scnt[k], 2); scnt[k] += __shfl_xor(scnt[k], 4);
  }
  sumd += __shfl_xor(sumd, 1); sumd += __shfl_xor(sumd, 2); sumd += __shfl_xor(sumd, 4);
#pragma unroll
  for (int k = 0; k < 3; ++k) {
    dmin[k] = fminf(dmin[k], __shfl_xor(dmin[k], 1));
    dmin[k] = fminf(dmin[k], __shfl_xor(dmin[k], 2));
    dmin[k] = fminf(dmin[k], __shfl_xor(dmin[k], 4));
  }
#pragma unroll
  for (int k = 0; k < 8; ++k) {
    smin[k] = fminf(smin[k], __shfl_xor(smin[k], 1));
    smin[k] = fminf(smin[k], __shfl_xor(smin[k], 2));
    smin[k] = fminf(smin[k], __shfl_xor(smin[k], 4));
  }

  if (jc == 0) {
    const bool own_unmasked = !isnan(sp[i].x);
    const float vcnt = fmaxf((float)(NPTS - M - (own_unmasked ? 1 : 0)), 1.0f);
    float* f = &xs[il * 33];
#pragma unroll
    for (int k = 0; k < 12; ++k) f[k] = cnt[k];
    f[12] = fminf(dmin[0] * 0.1f, 1.0f);
    f[13] = fminf(dmin[1] * 0.1f, 1.0f);
    f[14] = fminf(dmin[2] * 0.1f, 1.0f);
#pragma unroll
    for (int k = 0; k < 8; ++k) {
      f[15 + 2 * k] = scnt[k];
      f[16 + 2 * k] = fminf(smin[k] * 0.1f, 1.0f);
    }
    f[31] = cnt[9] + cnt[10] + cnt[11];
    f[32] = fminf(sumd / vcnt * 0.1f, 1.0f);
  }

  // ======================= MLP =======================
  const int w = tid >> 6;
  const int l = tid & 63;
  const float* __restrict__ xsf = xs + w * (RPW * 33);

  float xreg[5];
#pragma unroll
  for (int c = 0; c < 4; ++c) xreg[c] = xsf[c * 64 + l];
  xreg[4] = (l < 8) ? xsf[256 + l] : 0.0f;

  const v2f b1v = ((const v2f*)b1)[l];
  const v2f gav = ((const v2f*)gamma)[l];
  const v2f bev = ((const v2f*)beta)[l];
  const v2f* __restrict__ W1v = (const v2f*)W1;

  // ---- phase 1: h = x @ W1 + b1 (readlane broadcast + packed fma) ----
  v2f h[RPW];
#pragma unroll
  for (int r = 0; r < RPW; ++r) h[r] = b1v;
#pragma unroll
  for (int k = 0; k < 33; ++k) {
    const v2f wv = W1v[k * 64 + l];
#pragma unroll
    for (int r = 0; r < RPW; ++r) {
      const int v = r * 33 + k;
      pk_fma(h[r], rdlane(xreg[v >> 6], v & 63), wv);
    }
  }

  // ---- phase 2: LayerNorm + exact GELU ----
  float g0[RPW], g1[RPW];
#pragma unroll
  for (int r = 0; r < RPW; ++r) {
    float s = h[r].x + h[r].y;
#pragma unroll
    for (int o = 32; o > 0; o >>= 1) s += __shfl_xor(s, o);
    const float mu = s * 0.0078125f;
    const float d0 = h[r].x - mu, d1 = h[r].y - mu;
    float v = d0 * d0 + d1 * d1;
#pragma unroll
    for (int o = 32; o > 0; o >>= 1) v += __shfl_xor(v, o);
    const float inv = 1.0f / __fsqrt_rn(v * 0.0078125f + 1e-5f);
    float a = d0 * inv * gav.x + bev.x;
    float bb = d1 * inv * gav.y + bev.y;
    g0[r] = 0.5f * a * (1.0f + erff(a * 0.70710678118654752f));
    g1[r] = 0.5f * bb * (1.0f + erff(bb * 0.70710678118654752f));
  }

  // ---- alias barrier: all scru reads done above; gT overlays scru ----
  __syncthreads();
  unsigned short* gThi = (unsigned short*)scru;     // 32 rows x stride 136 bf16
  unsigned short* gTlo = gThi + 32 * 136;           // total 17408 B <= 21504 B
#pragma unroll
  for (int r = 0; r < RPW; ++r) {
    const unsigned short h0 = f2bf(g0[r]);
    const unsigned short h1 = f2bf(g1[r]);
    const unsigned short l0 = f2bf(g0[r] - bf2f(h0));
    const unsigned short l1 = f2bf(g1[r] - bf2f(h1));
    const int row = RPW * w + r;
    *(unsigned*)&gThi[row * 136 + 2 * l] = (unsigned)h0 | ((unsigned)h1 << 16);
    *(unsigned*)&gTlo[row * 136 + 2 * l] = (unsigned)l0 | ((unsigned)l1 << 16);
  }
  __syncthreads();   // cross-wave: A-frags read rows written by other waves

  // ---- phase 3: out = g @ W2 + b2 via MFMA (split-bf16, 3 products) ----
  const int mt = w & 1;            // M-tile (16 rows)
  const int ntb = (w >> 1) * 4;    // first of 4 N-tiles
  const int q = l >> 4, ln = l & 15;
  const int arow = mt * 16 + ln;

  f32x4 acc[4];
#pragma unroll
  for (int t = 0; t < 4; ++t) {
    const float bv = b2[(ntb + t) * 16 + ln];
    acc[t] = (f32x4){bv, bv, bv, bv};
  }
  const bf16x8* __restrict__ Bhi = (const bf16x8*)w2p;
  const bf16x8* __restrict__ Blo = Bhi + 2048;
#pragma unroll
  for (int kk = 0; kk < 4; ++kk) {
    const bf16x8 Ah = *(const bf16x8*)&gThi[arow * 136 + kk * 32 + q * 8];
    const bf16x8 Al = *(const bf16x8*)&gTlo[arow * 136 + kk * 32 + q * 8];
#pragma unroll
    for (int t = 0; t < 4; ++t) {
      const int fi = ((ntb + t) * 4 + kk) * 64 + l;
      const bf16x8 Bh = Bhi[fi];
      const bf16x8 Bl = Blo[fi];
      acc[t] = __builtin_amdgcn_mfma_f32_16x16x32_bf16(Ah, Bh, acc[t], 0, 0, 0);
      acc[t] = __builtin_amdgcn_mfma_f32_16x16x32_bf16(Ah, Bl, acc[t], 0, 0, 0);
      acc[t] = __builtin_amdgcn_mfma_f32_16x16x32_bf16(Al, Bh, acc[t], 0, 0, 0);
    }
  }
  const int gr0 = blockIdx.x * 32 + mt * 16 + q * 4;   // D row = quad*4 + reg
#pragma unroll
  for (int t = 0; t < 4; ++t) {
    const int col = (ntb + t) * 16 + ln;                // D col = lane&15
#pragma unroll
    for (int rg = 0; rg < 4; ++rg)
      out[(size_t)(gr0 + rg) * 128 + col] = acc[t][rg];
  }
}

extern "C" void kernel_launch(void* const* d_in, const int* in_sizes, int n_in,
                              void* d_out, int out_size, void* d_ws, size_t ws_size,
                              hipStream_t stream) {
  const float* positions = (const float*)d_in[0];
  const void*  kpm_raw   = d_in[1];
  const float* W1    = (const float*)d_in[2];
  const float* b1    = (const float*)d_in[3];
  const float* gamma = (const float*)d_in[4];
  const float* beta  = (const float*)d_in[5];
  const float* W2    = (const float*)d_in[6];
  const float* b2    = (const float*)d_in[7];
  float* out = (float*)d_out;
  unsigned short* w2p = (unsigned short*)d_ws;   // 64 KB: hi/lo bf16 B-frag planes

  w2prep<<<8, 256, 0, stream>>>(W2, w2p);
  fused_kernel<<<NBATCH * 16, 256, 0, stream>>>(positions, kpm_raw,
      W1, b1, gamma, beta, w2p, b2, out);
}